// Round 7
// baseline (40.437 us; speedup 1.0000x reference)
//
#include <hip/hip_runtime.h>

#define LPTS  2048   // points per row
#define NSEG  2047   // increments per row
#define TPB   128    // threads per row (2 waves)
#define STEPS 16     // segments per thread
#define NBATCH 2048
#define NWAVE (TPB / 64)

// Quotient signature state (7 floats): s[0]=a1x s[1]=a1y s[2]=a2xx s[3]=a2xy
// s[4]=a2yx s[5]=a2yy s[6]=z3 (= <WO3, a3>). Valid because a3 never feeds
// back into a1/a2 and the output only needs <WO3,a3>.

// s := s ⊗ sig(segment with increment v), z3-folded. Two parallel z-chains
// (depth ~4) instead of one serial chain (depth 7).
__device__ __forceinline__ void chen_step7(float s[7], float vx, float vy,
                                           const float WO[14], float WO78,
                                           float WO1112) {
    const float qxx = 0.5f * vx * vx;
    const float qxy = 0.5f * vx * vy;
    const float qyy = 0.5f * vy * vy;
    const float wx = fmaf(vx, (1.0f / 3.0f), s[0]);
    const float wy = fmaf(vy, (1.0f / 3.0f), s[1]);
    const float tvxx = fmaf(WO[7], vy, WO[6] * vx);
    const float tvxy = fmaf(WO[9], vy, WO[8] * vx);
    const float tvyx = fmaf(WO[11], vy, WO[10] * vx);
    const float tvyy = fmaf(WO[13], vy, WO[12] * vx);
    const float tqx = fmaf(WO[9], qyy, fmaf(WO78, qxy, WO[6] * qxx));
    const float tqy = fmaf(WO[13], qyy, fmaf(WO1112, qxy, WO[10] * qxx));
    float z1 = fmaf(s[2], tvxx, s[6]);
    z1 = fmaf(s[4], tvyx, z1);
    z1 = fmaf(wx, tqx, z1);
    float z2 = fmaf(s[5], tvyy, s[3] * tvxy);
    z2 = fmaf(wy, tqy, z2);
    s[6] = z1 + z2;
    const float ux = fmaf(vx, 0.5f, s[0]);
    const float uy = fmaf(vy, 0.5f, s[1]);
    s[2] = fmaf(ux, vx, s[2]);
    s[3] = fmaf(ux, vy, s[3]);
    s[4] = fmaf(uy, vx, s[4]);
    s[5] = fmaf(uy, vy, s[5]);
    s[0] += vx;
    s[1] += vy;
}

// b := a ⊗ b (a earlier), quotiented Chen combine. a == zeros is identity.
__device__ __forceinline__ void chen_combine7(const float a[7], float b[7],
                                              const float WO[14]) {
    const float tvxx = fmaf(WO[7], b[1], WO[6] * b[0]);
    const float tvxy = fmaf(WO[9], b[1], WO[8] * b[0]);
    const float tvyx = fmaf(WO[11], b[1], WO[10] * b[0]);
    const float tvyy = fmaf(WO[13], b[1], WO[12] * b[0]);
    const float ubx = fmaf(WO[9], b[5], fmaf(WO[8], b[4], fmaf(WO[7], b[3], WO[6] * b[2])));
    const float uby = fmaf(WO[13], b[5], fmaf(WO[12], b[4], fmaf(WO[11], b[3], WO[10] * b[2])));
    float z1 = fmaf(a[2], tvxx, a[6] + b[6]);
    z1 = fmaf(a[4], tvyx, z1);
    z1 = fmaf(a[0], ubx, z1);
    float z2 = fmaf(a[5], tvyy, a[3] * tvxy);
    z2 = fmaf(a[1], uby, z2);
    const float cxx = a[2] + fmaf(a[0], b[0], b[2]);
    const float cxy = a[3] + fmaf(a[0], b[1], b[3]);
    const float cyx = a[4] + fmaf(a[1], b[0], b[4]);
    const float cyy = a[5] + fmaf(a[1], b[1], b[5]);
    b[0] = a[0] + b[0];
    b[1] = a[1] + b[1];
    b[2] = cxx;
    b[3] = cxy;
    b[4] = cyx;
    b[5] = cyy;
    b[6] = z1 + z2;
}

// pointwise MLP 1 -> 8 -> 2 (ReLU between)
__device__ __forceinline__ void augment(float x,
                                        const float W1[8], const float B1[8],
                                        const float W2x[8], const float W2y[8],
                                        float B2x, float B2y,
                                        float& px, float& py) {
    float ox = B2x, oy = B2y;
#pragma unroll
    for (int c = 0; c < 8; ++c) {
        float h = fmaxf(fmaf(W1[c], x, B1[c]), 0.0f);
        ox = fmaf(W2x[c], h, ox);
        oy = fmaf(W2y[c], h, oy);
    }
    px = ox;
    py = oy;
}

__global__ void sig_scan_kernel(
    const float* __restrict__ x, const float* __restrict__ w1,
    const float* __restrict__ b1, const float* __restrict__ w2,
    const float* __restrict__ b2, const float* __restrict__ wout,
    float* __restrict__ out) {
    __shared__ float wsum[8];  // wave-0 total (NWAVE==2)

    const int t = threadIdx.x;
    const int lane = t & 63;
    const int wv = t >> 6;
    const int brow = blockIdx.x;
    const float* __restrict__ xrow = x + (size_t)brow * LPTS;

    // uniform weights -> scalar loads (SGPRs)
    float W1[8], B1[8], W2x[8], W2y[8];
#pragma unroll
    for (int c = 0; c < 8; ++c) {
        W1[c] = w1[c];
        B1[c] = b1[c];
        W2x[c] = w2[c];
        W2y[c] = w2[8 + c];
    }
    const float B2x = b2[0], B2y = b2[1];
    float WO[14];
#pragma unroll
    for (int i = 0; i < 14; ++i) WO[i] = wout[i];
    const float WO78 = WO[7] + WO[8];
    const float WO1112 = WO[11] + WO[12];

    // ---- phase 1: stream 17 points, increments, local 7-state sig ----
    const int n0 = t * STEPS;
    float vx[STEPS], vy[STEPS];
    float s[7] = {0, 0, 0, 0, 0, 0, 0};

    float ppx, ppy;
    {
        const float4 x0 = *reinterpret_cast<const float4*>(xrow + n0);
        augment(x0.x, W1, B1, W2x, W2y, B2x, B2y, ppx, ppy);
        float px, py;
        augment(x0.y, W1, B1, W2x, W2y, B2x, B2y, px, py);
        vx[0] = px - ppx; vy[0] = py - ppy; ppx = px; ppy = py;
        augment(x0.z, W1, B1, W2x, W2y, B2x, B2y, px, py);
        vx[1] = px - ppx; vy[1] = py - ppy; ppx = px; ppy = py;
        augment(x0.w, W1, B1, W2x, W2y, B2x, B2y, px, py);
        vx[2] = px - ppx; vy[2] = py - ppy; ppx = px; ppy = py;
#pragma unroll
        for (int q = 1; q < 4; ++q) {
            const float4 xq = *reinterpret_cast<const float4*>(xrow + n0 + 4 * q);
            augment(xq.x, W1, B1, W2x, W2y, B2x, B2y, px, py);
            vx[4 * q - 1] = px - ppx; vy[4 * q - 1] = py - ppy; ppx = px; ppy = py;
            augment(xq.y, W1, B1, W2x, W2y, B2x, B2y, px, py);
            vx[4 * q + 0] = px - ppx; vy[4 * q + 0] = py - ppy; ppx = px; ppy = py;
            augment(xq.z, W1, B1, W2x, W2y, B2x, B2y, px, py);
            vx[4 * q + 1] = px - ppx; vy[4 * q + 1] = py - ppy; ppx = px; ppy = py;
            augment(xq.w, W1, B1, W2x, W2y, B2x, B2y, px, py);
            vx[4 * q + 2] = px - ppx; vy[4 * q + 2] = py - ppy; ppx = px; ppy = py;
        }
        const int ib = (n0 + STEPS > LPTS - 1) ? (LPTS - 1) : (n0 + STEPS);
        augment(xrow[ib], W1, B1, W2x, W2y, B2x, B2y, px, py);
        vx[STEPS - 1] = px - ppx; vy[STEPS - 1] = py - ppy;
    }
#pragma unroll
    for (int k = 0; k < STEPS; ++k)
        chen_step7(s, vx[k], vy[k], WO, WO78, WO1112);

    // ---- phase 2a: wave64 inclusive shuffle scan (7-wide) ----
#pragma unroll
    for (int off = 1; off < 64; off <<= 1) {
        float p[7];
#pragma unroll
        for (int i = 0; i < 7; ++i) p[i] = __shfl_up(s[i], (unsigned)off);
        if (lane >= off) chen_combine7(p, s, WO);
    }

    // ---- phase 2b: cross-wave combine (one barrier, broadcast read) ----
    if (t == 63) {
#pragma unroll
        for (int i = 0; i < 7; ++i) wsum[i] = s[i];
    }
    __syncthreads();

    float a[7];  // exclusive carry
    {
        float e[7];
#pragma unroll
        for (int i = 0; i < 7; ++i) e[i] = __shfl_up(s[i], 1u);
#pragma unroll
        for (int i = 0; i < 7; ++i) a[i] = (lane == 0) ? 0.0f : e[i];
    }
    if (wv == 1) {
        float tw[7];
#pragma unroll
        for (int i = 0; i < 7; ++i) tw[i] = wsum[i];  // broadcast read
        chen_combine7(tw, a, WO);  // zeros-identity safe at lane 0
    }

    // ---- phase 3: replay with carry, project, direct store ----
    float* __restrict__ orow = out + (size_t)brow * NSEG;
#pragma unroll
    for (int k = 0; k < STEPS; ++k) {
        chen_step7(a, vx[k], vy[k], WO, WO78, WO1112);
        float o = a[6];
        o = fmaf(WO[0], a[0], o);
        o = fmaf(WO[1], a[1], o);
        o = fmaf(WO[2], a[2], o);
        o = fmaf(WO[3], a[3], o);
        o = fmaf(WO[4], a[4], o);
        o = fmaf(WO[5], a[5], o);
        const int n = n0 + k;
        if (n < NSEG) orow[n] = o;
    }
}

extern "C" void kernel_launch(void* const* d_in, const int* in_sizes, int n_in,
                              void* d_out, int out_size, void* d_ws, size_t ws_size,
                              hipStream_t stream) {
    const float* x  = (const float*)d_in[0];
    const float* w1 = (const float*)d_in[1];
    const float* b1 = (const float*)d_in[2];
    const float* w2 = (const float*)d_in[3];
    const float* b2 = (const float*)d_in[4];
    const float* wo = (const float*)d_in[5];
    float* out = (float*)d_out;
    sig_scan_kernel<<<NBATCH, TPB, 0, stream>>>(x, w1, b1, w2, b2, wo, out);
}

// Round 8
// 32.023 us; speedup vs baseline: 1.2627x; 1.2627x over previous
//
#include <hip/hip_runtime.h>

#define LPTS  2048   // points per row
#define NSEG  2047   // increments per row
#define TPB   128    // threads per row (2 waves)
#define STEPS 16     // segments per thread
#define NBATCH 2048
#define NWAVE (TPB / 64)

// Quotient signature state (7 floats): s[0]=a1x s[1]=a1y s[2]=a2xx s[3]=a2xy
// s[4]=a2yx s[5]=a2yy s[6]=z3 (= <WO3, a3>). Valid because a3 never feeds
// back into a1/a2 and the output only needs <WO3,a3>.

// s := s ⊗ sig(segment with increment v), z3-folded. Two parallel z-chains.
__device__ __forceinline__ void chen_step7(float s[7], float vx, float vy,
                                           const float WO[14], float WO78,
                                           float WO1112) {
    const float qxx = 0.5f * vx * vx;
    const float qxy = 0.5f * vx * vy;
    const float qyy = 0.5f * vy * vy;
    const float wx = fmaf(vx, (1.0f / 3.0f), s[0]);
    const float wy = fmaf(vy, (1.0f / 3.0f), s[1]);
    const float tvxx = fmaf(WO[7], vy, WO[6] * vx);
    const float tvxy = fmaf(WO[9], vy, WO[8] * vx);
    const float tvyx = fmaf(WO[11], vy, WO[10] * vx);
    const float tvyy = fmaf(WO[13], vy, WO[12] * vx);
    const float tqx = fmaf(WO[9], qyy, fmaf(WO78, qxy, WO[6] * qxx));
    const float tqy = fmaf(WO[13], qyy, fmaf(WO1112, qxy, WO[10] * qxx));
    float z1 = fmaf(s[2], tvxx, s[6]);
    z1 = fmaf(s[4], tvyx, z1);
    z1 = fmaf(wx, tqx, z1);
    float z2 = fmaf(s[5], tvyy, s[3] * tvxy);
    z2 = fmaf(wy, tqy, z2);
    s[6] = z1 + z2;
    const float ux = fmaf(vx, 0.5f, s[0]);
    const float uy = fmaf(vy, 0.5f, s[1]);
    s[2] = fmaf(ux, vx, s[2]);
    s[3] = fmaf(ux, vy, s[3]);
    s[4] = fmaf(uy, vx, s[4]);
    s[5] = fmaf(uy, vy, s[5]);
    s[0] += vx;
    s[1] += vy;
}

// b := a ⊗ b (a earlier), quotiented Chen combine. a == zeros is identity.
__device__ __forceinline__ void chen_combine7(const float a[7], float b[7],
                                              const float WO[14]) {
    const float tvxx = fmaf(WO[7], b[1], WO[6] * b[0]);
    const float tvxy = fmaf(WO[9], b[1], WO[8] * b[0]);
    const float tvyx = fmaf(WO[11], b[1], WO[10] * b[0]);
    const float tvyy = fmaf(WO[13], b[1], WO[12] * b[0]);
    const float ubx = fmaf(WO[9], b[5], fmaf(WO[8], b[4], fmaf(WO[7], b[3], WO[6] * b[2])));
    const float uby = fmaf(WO[13], b[5], fmaf(WO[12], b[4], fmaf(WO[11], b[3], WO[10] * b[2])));
    float z1 = fmaf(a[2], tvxx, a[6] + b[6]);
    z1 = fmaf(a[4], tvyx, z1);
    z1 = fmaf(a[0], ubx, z1);
    float z2 = fmaf(a[5], tvyy, a[3] * tvxy);
    z2 = fmaf(a[1], uby, z2);
    const float cxx = a[2] + fmaf(a[0], b[0], b[2]);
    const float cxy = a[3] + fmaf(a[0], b[1], b[3]);
    const float cyx = a[4] + fmaf(a[1], b[0], b[4]);
    const float cyy = a[5] + fmaf(a[1], b[1], b[5]);
    b[0] = a[0] + b[0];
    b[1] = a[1] + b[1];
    b[2] = cxx;
    b[3] = cxy;
    b[4] = cyx;
    b[5] = cyy;
    b[6] = z1 + z2;
}

// pointwise MLP 1 -> 8 -> 2 (ReLU between)
__device__ __forceinline__ void augment(float x,
                                        const float W1[8], const float B1[8],
                                        const float W2x[8], const float W2y[8],
                                        float B2x, float B2y,
                                        float& px, float& py) {
    float ox = B2x, oy = B2y;
#pragma unroll
    for (int c = 0; c < 8; ++c) {
        float h = fmaxf(fmaf(W1[c], x, B1[c]), 0.0f);
        ox = fmaf(W2x[c], h, ox);
        oy = fmaf(W2y[c], h, oy);
    }
    px = ox;
    py = oy;
}

__global__ __launch_bounds__(TPB, 2) void sig_scan_kernel(
    const float* __restrict__ x, const float* __restrict__ w1,
    const float* __restrict__ b1, const float* __restrict__ w2,
    const float* __restrict__ b2, const float* __restrict__ wout,
    float* __restrict__ out) {
    __shared__ float wsum[8];  // wave-0 total (NWAVE==2)

    const int t = threadIdx.x;
    const int lane = t & 63;
    const int wv = t >> 6;
    const int brow = blockIdx.x;
    const float* __restrict__ xrow = x + (size_t)brow * LPTS;

    // uniform weights -> scalar loads (SGPRs)
    float W1[8], B1[8], W2x[8], W2y[8];
#pragma unroll
    for (int c = 0; c < 8; ++c) {
        W1[c] = w1[c];
        B1[c] = b1[c];
        W2x[c] = w2[c];
        W2y[c] = w2[8 + c];
    }
    const float B2x = b2[0], B2y = b2[1];
    float WO[14];
#pragma unroll
    for (int i = 0; i < 14; ++i) WO[i] = wout[i];
    const float WO78 = WO[7] + WO[8];
    const float WO1112 = WO[11] + WO[12];

    // ---- phase 1: stream 17 points, increments, local 7-state sig ----
    const int n0 = t * STEPS;
    float vx[STEPS], vy[STEPS];
    float s[7] = {0, 0, 0, 0, 0, 0, 0};

    float ppx, ppy;
    {
        const float4 x0 = *reinterpret_cast<const float4*>(xrow + n0);
        augment(x0.x, W1, B1, W2x, W2y, B2x, B2y, ppx, ppy);
        float px, py;
        augment(x0.y, W1, B1, W2x, W2y, B2x, B2y, px, py);
        vx[0] = px - ppx; vy[0] = py - ppy; ppx = px; ppy = py;
        augment(x0.z, W1, B1, W2x, W2y, B2x, B2y, px, py);
        vx[1] = px - ppx; vy[1] = py - ppy; ppx = px; ppy = py;
        augment(x0.w, W1, B1, W2x, W2y, B2x, B2y, px, py);
        vx[2] = px - ppx; vy[2] = py - ppy; ppx = px; ppy = py;
#pragma unroll
        for (int q = 1; q < 4; ++q) {
            const float4 xq = *reinterpret_cast<const float4*>(xrow + n0 + 4 * q);
            augment(xq.x, W1, B1, W2x, W2y, B2x, B2y, px, py);
            vx[4 * q - 1] = px - ppx; vy[4 * q - 1] = py - ppy; ppx = px; ppy = py;
            augment(xq.y, W1, B1, W2x, W2y, B2x, B2y, px, py);
            vx[4 * q + 0] = px - ppx; vy[4 * q + 0] = py - ppy; ppx = px; ppy = py;
            augment(xq.z, W1, B1, W2x, W2y, B2x, B2y, px, py);
            vx[4 * q + 1] = px - ppx; vy[4 * q + 1] = py - ppy; ppx = px; ppy = py;
            augment(xq.w, W1, B1, W2x, W2y, B2x, B2y, px, py);
            vx[4 * q + 2] = px - ppx; vy[4 * q + 2] = py - ppy; ppx = px; ppy = py;
        }
        const int ib = (n0 + STEPS > LPTS - 1) ? (LPTS - 1) : (n0 + STEPS);
        augment(xrow[ib], W1, B1, W2x, W2y, B2x, B2y, px, py);
        vx[STEPS - 1] = px - ppx; vy[STEPS - 1] = py - ppy;
    }
#pragma unroll
    for (int k = 0; k < STEPS; ++k)
        chen_step7(s, vx[k], vy[k], WO, WO78, WO1112);

    // ---- phase 2a: wave64 inclusive shuffle scan (7-wide) ----
#pragma unroll
    for (int off = 1; off < 64; off <<= 1) {
        float p[7];
#pragma unroll
        for (int i = 0; i < 7; ++i) p[i] = __shfl_up(s[i], (unsigned)off);
        if (lane >= off) chen_combine7(p, s, WO);
    }

    // ---- phase 2b: cross-wave combine (one barrier, broadcast read) ----
    if (t == 63) {
#pragma unroll
        for (int i = 0; i < 7; ++i) wsum[i] = s[i];
    }
    __syncthreads();

    float a[7];  // exclusive carry
    {
        float e[7];
#pragma unroll
        for (int i = 0; i < 7; ++i) e[i] = __shfl_up(s[i], 1u);
#pragma unroll
        for (int i = 0; i < 7; ++i) a[i] = (lane == 0) ? 0.0f : e[i];
    }
    if (wv == 1) {
        float tw[7];
#pragma unroll
        for (int i = 0; i < 7; ++i) tw[i] = wsum[i];  // broadcast read
        chen_combine7(tw, a, WO);  // zeros-identity safe at lane 0
    }

    // ---- phase 3: replay with carry, project, direct store ----
    float* __restrict__ orow = out + (size_t)brow * NSEG;
#pragma unroll
    for (int k = 0; k < STEPS; ++k) {
        chen_step7(a, vx[k], vy[k], WO, WO78, WO1112);
        float o = a[6];
        o = fmaf(WO[0], a[0], o);
        o = fmaf(WO[1], a[1], o);
        o = fmaf(WO[2], a[2], o);
        o = fmaf(WO[3], a[3], o);
        o = fmaf(WO[4], a[4], o);
        o = fmaf(WO[5], a[5], o);
        const int n = n0 + k;
        if (n < NSEG) orow[n] = o;
    }
}

extern "C" void kernel_launch(void* const* d_in, const int* in_sizes, int n_in,
                              void* d_out, int out_size, void* d_ws, size_t ws_size,
                              hipStream_t stream) {
    const float* x  = (const float*)d_in[0];
    const float* w1 = (const float*)d_in[1];
    const float* b1 = (const float*)d_in[2];
    const float* w2 = (const float*)d_in[3];
    const float* b2 = (const float*)d_in[4];
    const float* wo = (const float*)d_in[5];
    float* out = (float*)d_out;
    sig_scan_kernel<<<NBATCH, TPB, 0, stream>>>(x, w1, b1, w2, b2, wo, out);
}

// Round 9
// 21.599 us; speedup vs baseline: 1.8721x; 1.4826x over previous
//
#include <hip/hip_runtime.h>

#define LPTS  2048   // points per row
#define NSEG  2047   // increments per row
#define TPB   256
#define STEPS 8      // segments per thread
#define NBATCH 2048
#define NWAVE (TPB / 64)

typedef float v2f __attribute__((ext_vector_type(2)));

__device__ __forceinline__ v2f bc(float x) { return (v2f){x, x}; }
__device__ __forceinline__ v2f vfma(v2f a, v2f b, v2f c) {
    return __builtin_elementwise_fma(a, b, c);
}

// Quotient signature state: s1=(a1x,a1y), A=(a2xx,a2yx), B=(a2xy,a2yy),
// z = <WO3, a3>. Valid: a3 never feeds back into a1/a2; output needs only z.
// Packed so x/y-symmetric math maps to v_pk_fma_f32 (full-rate on gfx950).

struct SigK {                      // wave-uniform constants
    v2f C0, C1, C2, C3, D1;        // TV/TQ projections of WO3
    v2f P01, P24, P35, B2v;        // output proj pairs, conv2 bias
    v2f W1p[4], B1p[4], WP[8];     // augment MLP packed weights
};

// s := s ⊗ sig(segment v)
__device__ __forceinline__ void chen_step(v2f& s1, v2f& A, v2f& B, float& z,
                                          v2f v, const SigK& K) {
    const v2f q2 = (v * v) * 0.5f;            // (qxx, qyy)
    const float qxy = 0.5f * v.x * v.y;
    const v2f TVx = vfma(K.C1, bc(v.y), K.C0 * v.x);
    const v2f TVy = vfma(K.C3, bc(v.y), K.C2 * v.x);
    const v2f TQ = vfma(K.C0, bc(q2.x), vfma(K.D1, bc(qxy), K.C3 * q2.y));
    const v2f w = vfma(v, bc(1.0f / 3.0f), s1);
    v2f zv = vfma(A, TVx, (v2f){z, 0.0f});
    zv = vfma(B, TVy, zv);
    zv = vfma(w, TQ, zv);
    z = zv.x + zv.y;
    const v2f u = vfma(v, bc(0.5f), s1);
    A = vfma(u, bc(v.x), A);
    B = vfma(u, bc(v.y), B);
    s1 = s1 + v;
}

// b := a ⊗ b (a earlier). a == zeros acts as identity.
__device__ __forceinline__ void chen_combine(v2f a1, v2f aA, v2f aB, float az,
                                             v2f& b1, v2f& bA, v2f& bB, float& bz,
                                             const SigK& K) {
    const v2f TVx = vfma(K.C1, bc(b1.y), K.C0 * b1.x);
    const v2f TVy = vfma(K.C3, bc(b1.y), K.C2 * b1.x);
    const v2f UB = vfma(K.C3, bc(bB.y),
                   vfma(K.C2, bc(bA.y), vfma(K.C1, bc(bB.x), K.C0 * bA.x)));
    v2f zv = vfma(aA, TVx, (v2f){az + bz, 0.0f});
    zv = vfma(aB, TVy, zv);
    zv = vfma(a1, UB, zv);
    bz = zv.x + zv.y;
    bA = vfma(a1, bc(b1.x), aA + bA);
    bB = vfma(a1, bc(b1.y), aB + bB);
    b1 = a1 + b1;
}

// pointwise MLP 1 -> 8 -> 2 (ReLU between), packed channels
__device__ __forceinline__ v2f augment2(float x, const SigK& K) {
    v2f o = K.B2v;
#pragma unroll
    for (int j = 0; j < 4; ++j) {
        v2f h = vfma(K.W1p[j], bc(x), K.B1p[j]);
        h = __builtin_elementwise_max(h, bc(0.0f));
        o = vfma(K.WP[2 * j], bc(h.x), o);
        o = vfma(K.WP[2 * j + 1], bc(h.y), o);
    }
    return o;
}

__global__ void sig_scan_kernel(
    const float* __restrict__ x, const float* __restrict__ w1,
    const float* __restrict__ b1, const float* __restrict__ w2,
    const float* __restrict__ b2, const float* __restrict__ wout,
    float* __restrict__ out) {
    __shared__ float wsum[NWAVE][8];

    const int t = threadIdx.x;
    const int lane = t & 63;
    const int wv = t >> 6;
    const int brow = blockIdx.x;
    const float* __restrict__ xrow = x + (size_t)brow * LPTS;

    // wave-uniform constants (scalar loads)
    SigK K;
    float WO[14];
#pragma unroll
    for (int i = 0; i < 14; ++i) WO[i] = wout[i];
    K.C0 = (v2f){WO[6], WO[10]};
    K.C1 = (v2f){WO[7], WO[11]};
    K.C2 = (v2f){WO[8], WO[12]};
    K.C3 = (v2f){WO[9], WO[13]};
    K.D1 = (v2f){WO[7] + WO[8], WO[11] + WO[12]};
    K.P01 = (v2f){WO[0], WO[1]};
    K.P24 = (v2f){WO[2], WO[4]};
    K.P35 = (v2f){WO[3], WO[5]};
    K.B2v = (v2f){b2[0], b2[1]};
#pragma unroll
    for (int j = 0; j < 4; ++j) {
        K.W1p[j] = (v2f){w1[2 * j], w1[2 * j + 1]};
        K.B1p[j] = (v2f){b1[2 * j], b1[2 * j + 1]};
    }
#pragma unroll
    for (int c = 0; c < 8; ++c) K.WP[c] = (v2f){w2[c], w2[8 + c]};

    // ---- phase 1: load 9 points, augment, increments, local sig ----
    const int n0 = t * STEPS;
    const float4 xa = *reinterpret_cast<const float4*>(xrow + n0);
    const float4 xb = *reinterpret_cast<const float4*>(xrow + n0 + 4);
    const int ib = (n0 + STEPS > LPTS - 1) ? (LPTS - 1) : (n0 + STEPS);
    const float x8 = xrow[ib];  // clamped -> v=0 identity for last thread
    const float xv[STEPS + 1] = {xa.x, xa.y, xa.z, xa.w,
                                 xb.x, xb.y, xb.z, xb.w, x8};

    v2f vseg[STEPS];
    v2f s1 = bc(0.0f), A = bc(0.0f), B = bc(0.0f);
    float z = 0.0f;
    v2f pp = augment2(xv[0], K);
#pragma unroll
    for (int k = 0; k < STEPS; ++k) {
        const v2f p = augment2(xv[k + 1], K);
        vseg[k] = p - pp;
        pp = p;
        chen_step(s1, A, B, z, vseg[k], K);
    }

    // ---- phase 2a: wave64 inclusive shuffle scan ----
#pragma unroll
    for (int off = 1; off < 64; off <<= 1) {
        v2f p1, pA, pB;
        float pz;
        p1.x = __shfl_up(s1.x, (unsigned)off);
        p1.y = __shfl_up(s1.y, (unsigned)off);
        pA.x = __shfl_up(A.x, (unsigned)off);
        pA.y = __shfl_up(A.y, (unsigned)off);
        pB.x = __shfl_up(B.x, (unsigned)off);
        pB.y = __shfl_up(B.y, (unsigned)off);
        pz = __shfl_up(z, (unsigned)off);
        if (lane >= off) chen_combine(p1, pA, pB, pz, s1, A, B, z, K);
    }

    // ---- phase 2b: cross-wave combine (one barrier, broadcast reads) ----
    if (lane == 63) {
        wsum[wv][0] = s1.x; wsum[wv][1] = s1.y;
        wsum[wv][2] = A.x;  wsum[wv][3] = A.y;
        wsum[wv][4] = B.x;  wsum[wv][5] = B.y;
        wsum[wv][6] = z;
    }
    __syncthreads();

    // exclusive carry
    v2f c1, cA, cB;
    float cz;
    {
        float e0 = __shfl_up(s1.x, 1u), e1 = __shfl_up(s1.y, 1u);
        float e2 = __shfl_up(A.x, 1u), e3 = __shfl_up(A.y, 1u);
        float e4 = __shfl_up(B.x, 1u), e5 = __shfl_up(B.y, 1u);
        float e6 = __shfl_up(z, 1u);
        const bool z0 = (lane == 0);
        c1 = (v2f){z0 ? 0.0f : e0, z0 ? 0.0f : e1};
        cA = (v2f){z0 ? 0.0f : e2, z0 ? 0.0f : e3};
        cB = (v2f){z0 ? 0.0f : e4, z0 ? 0.0f : e5};
        cz = z0 ? 0.0f : e6;
    }
    for (int w = wv - 1; w >= 0; --w) {
        const v2f t1 = (v2f){wsum[w][0], wsum[w][1]};
        const v2f tA = (v2f){wsum[w][2], wsum[w][3]};
        const v2f tB = (v2f){wsum[w][4], wsum[w][5]};
        const float tz = wsum[w][6];
        chen_combine(t1, tA, tB, tz, c1, cA, cB, cz, K);
    }

    // ---- phase 3: replay with carry, project, direct store ----
    float* __restrict__ orow = out + (size_t)brow * NSEG;
#pragma unroll
    for (int k = 0; k < STEPS; ++k) {
        chen_step(c1, cA, cB, cz, vseg[k], K);
        v2f ov = vfma(c1, K.P01, (v2f){cz, 0.0f});
        ov = vfma(cA, K.P24, ov);
        ov = vfma(cB, K.P35, ov);
        const float o = ov.x + ov.y;
        const int n = n0 + k;
        if (n < NSEG) orow[n] = o;
    }
}

extern "C" void kernel_launch(void* const* d_in, const int* in_sizes, int n_in,
                              void* d_out, int out_size, void* d_ws, size_t ws_size,
                              hipStream_t stream) {
    const float* x  = (const float*)d_in[0];
    const float* w1 = (const float*)d_in[1];
    const float* b1 = (const float*)d_in[2];
    const float* w2 = (const float*)d_in[3];
    const float* b2 = (const float*)d_in[4];
    const float* wo = (const float*)d_in[5];
    float* out = (float*)d_out;
    sig_scan_kernel<<<NBATCH, TPB, 0, stream>>>(x, w1, b1, w2, b2, wo, out);
}